// Round 6
// baseline (316.671 us; speedup 1.0000x reference)
//
#include <hip/hip_runtime.h>
#include <math.h>

// 10-layer MLP, fp16 MFMA (fp32 acc), 16-row tiles, grid-stride per wave.
// R6: (a) activations ALSO fragment-packed in LDS (read = lane*16B linear,
// zero bank conflicts; R5's ACT_W=72 row layout was an 8-way conflict on
// every B-frag read); (b) 512-thread blocks sharing one weight copy ->
// LDS 46080 B/block -> 3 blocks/CU = 24 waves/CU (75%) to hide the per-layer
// LDS round-trip; (c) acc init folded into first MFMA via shared zero C.
// Bias folded as augmented-K column (marker 1.0 at feature==OUT).

typedef _Float16 half8 __attribute__((ext_vector_type(8)));
typedef _Float16 half4 __attribute__((ext_vector_type(4)));
typedef _Float16 half2 __attribute__((ext_vector_type(2)));
typedef float f32x4 __attribute__((ext_vector_type(4)));

__device__ __forceinline__ float swish_f(float a) {
    float e = __expf(-a);
    return a * __builtin_amdgcn_rcpf(1.0f + e);
}

// One lane's 8 f16 of weight fragment (ot,kt): A-frag layout row=ot*16+lr,
// k=kt*32+kg*8+e. Column k==IN holds the bias (augmented-K); else zero-pad.
__device__ __forceinline__ half8 make_frag(const float* __restrict__ W,
                                           const float* __restrict__ b,
                                           int IN, int OUT, int ot, int kt,
                                           int lr, int kg) {
    const int r = ot * 16 + lr;
    half8 h;
#pragma unroll
    for (int e = 0; e < 8; ++e) {
        const int k = kt * 32 + kg * 8 + e;
        float v = 0.0f;
        if (r < OUT) {
            if (k < IN)
                v = W[r * IN + k];
            else if (k == IN)
                v = b[r];
        }
        h[e] = (_Float16)v;
    }
    return h;
}

// acc[ot][r] = feature ot*16+kg*4+r of sample lr (D^T). Swish all (pad accs
// are 0 -> swish 0), overwrite feature==OUT with 1.0 marker, cvt_pkrtz pack,
// one b64 store into the frag-packed act tile:
//   feature f of sample lr lives at (f>>5)*512 + (((f>>3)&3)*16 + lr)*8 + (f&7)
//   (f16 units); the 4 features of (ot,kg) share one run: kt=ot>>1 (compile
//   time), lane-group (2ot+(kg>>1))&3, half-select kg&1.
template <int NOT, int OUT>
__device__ __forceinline__ void epilogue(const f32x4 (&acc)[NOT],
                                         _Float16* act, int lr, int kg) {
    const int kgl = kg & 1;
    const int kgh = kg >> 1;
#pragma unroll
    for (int ot = 0; ot < NOT; ++ot) {
        float v[4];
#pragma unroll
        for (int r = 0; r < 4; ++r) {
            v[r] = swish_f(acc[ot][r]);
            if (ot == OUT / 16 && ot * 16 + kg * 4 + r == OUT) v[r] = 1.0f;
        }
        auto lo = __builtin_amdgcn_cvt_pkrtz(v[0], v[1]);
        auto hi = __builtin_amdgcn_cvt_pkrtz(v[2], v[3]);
        union {
            half4 h4;
            half2 h2[2];
        } u;
        u.h2[0] = __builtin_bit_cast(half2, lo);
        u.h2[1] = __builtin_bit_cast(half2, hi);
        _Float16* p = act + (ot >> 1) * 512 +
                      (((2 * ot + kgh) & 3) * 16 + lr) * 8 + kgl * 4;
        *(half4*)p = u.h4;
    }
}

// One layer; weight frags + act frags both read at lane*16B (conflict-free).
template <int NOT, int NKT, int OUT>
__device__ __forceinline__ void layer(const _Float16* __restrict__ wb,
                                      _Float16* act, int lane, int lr, int kg,
                                      f32x4 z4) {
    f32x4 acc[NOT];
#pragma unroll
    for (int kt = 0; kt < NKT; ++kt) {
        const half8 bf = *(const half8*)(act + kt * 512 + lane * 8);
#pragma unroll
        for (int ot = 0; ot < NOT; ++ot) {
            const half8 wf =
                *(const half8*)(wb + (ot * NKT + kt) * 512 + lane * 8);
            acc[ot] = __builtin_amdgcn_mfma_f32_16x16x32_f16(
                wf, bf, kt == 0 ? z4 : acc[ot], 0, 0, 0);
        }
    }
    epilogue<NOT, OUT>(acc, act, lr, kg);
}

__global__ __launch_bounds__(512, 6) void longnet_mlp_r6(
    const float* __restrict__ x,
    const float* __restrict__ W0, const float* __restrict__ b0,
    const float* __restrict__ W1, const float* __restrict__ b1,
    const float* __restrict__ W2, const float* __restrict__ b2,
    const float* __restrict__ W3, const float* __restrict__ b3,
    const float* __restrict__ W4, const float* __restrict__ b4,
    const float* __restrict__ W5, const float* __restrict__ b5,
    const float* __restrict__ W6, const float* __restrict__ b6,
    const float* __restrict__ W7, const float* __restrict__ b7,
    const float* __restrict__ W8, const float* __restrict__ b8,
    const float* __restrict__ W9, const float* __restrict__ b9,
    float* __restrict__ out, int n) {
    // 29 weight frags x 1024 B = 29696 B + 8 waves x 2048 B act = 46080 B
    // -> 3 blocks/CU, 24 waves/CU.
    __shared__ __align__(16) _Float16 s_w[29 * 512];
    __shared__ __align__(16) _Float16 s_act[8 * 1024];

    const int tid = threadIdx.x;
    const int lane = tid & 63;
    const int wave = tid >> 6;
    const int lr = lane & 15;
    const int kg = lane >> 4;

    // ---- stage 29 weight frags into LDS (8 waves split round-robin) ----
    {
        const float* Wt[10] = {W0, W1, W2, W3, W4, W5, W6, W7, W8, W9};
        const float* bt[10] = {b0, b1, b2, b3, b4, b5, b6, b7, b8, b9};
        const int INs[10] = {11, 20, 20, 30, 30, 40, 40, 40, 20, 10};
        const int OUTs[10] = {20, 20, 30, 30, 40, 40, 40, 20, 10, 1};
        const int NOTs[10] = {2, 2, 2, 2, 3, 3, 3, 2, 1, 1};
        const int NKTs[10] = {1, 1, 1, 1, 1, 2, 2, 2, 1, 1};
        int f = 0;
        for (int L = 0; L < 10; ++L)
            for (int ot = 0; ot < NOTs[L]; ++ot)
                for (int kt = 0; kt < NKTs[L]; ++kt, ++f)
                    if ((f & 7) == wave) {
                        half8 h = make_frag(Wt[L], bt[L], INs[L], OUTs[L], ot,
                                            kt, lr, kg);
                        *(half8*)(s_w + f * 512 + lane * 8) = h;
                    }
    }

    _Float16* act = s_act + wave * 1024;
    // zero wave's act tile once; kt1 lanes kg'>=2 (features 48..63) stay
    // zero forever (K-pad for the IN_P=64 layers, never written).
    {
        int* a32 = (int*)act;
#pragma unroll
        for (int i = 0; i < 8; ++i) a32[i * 64 + lane] = 0;
    }
    __syncthreads();

    const f32x4 z4 = (f32x4){0.f, 0.f, 0.f, 0.f};
    const int ntile = n >> 4;  // n = 2e6, divisible by 16
    const int step = (int)gridDim.x * 8;

    for (int t = blockIdx.x * 8 + wave; t < ntile; t += step) {
        const int row0 = t * 16;

        // layer-0 B-frag straight from global x: col=sample(lr), k=feature;
        // feature 11 = 1.0 bias marker. kg>=2 lanes are all K-pad (zero).
        half8 xb = {};
        if (kg < 2) {
            const float* xr = x + (size_t)(row0 + lr) * 11 + kg * 8;
#pragma unroll
            for (int e = 0; e < 8; ++e) {
                const int k = kg * 8 + e;
                float v = (k < 11) ? xr[e] : ((k == 11) ? 1.0f : 0.0f);
                xb[e] = (_Float16)v;
            }
        }

        // layer 0 from registers (x), rest act<->act in LDS.
        {
            f32x4 acc[2];
#pragma unroll
            for (int ot = 0; ot < 2; ++ot) {
                const half8 wf = *(const half8*)(s_w + ot * 512 + lane * 8);
                acc[ot] = __builtin_amdgcn_mfma_f32_16x16x32_f16(wf, xb, z4,
                                                                 0, 0, 0);
            }
            epilogue<2, 20>(acc, act, lr, kg);
        }
        layer<2, 1, 20>(s_w + 2 * 512, act, lane, lr, kg, z4);
        layer<2, 1, 30>(s_w + 4 * 512, act, lane, lr, kg, z4);
        layer<2, 1, 30>(s_w + 6 * 512, act, lane, lr, kg, z4);
        layer<3, 1, 40>(s_w + 8 * 512, act, lane, lr, kg, z4);
        layer<3, 2, 40>(s_w + 11 * 512, act, lane, lr, kg, z4);
        layer<3, 2, 40>(s_w + 17 * 512, act, lane, lr, kg, z4);
        layer<2, 2, 20>(s_w + 23 * 512, act, lane, lr, kg, z4);
        // L8 (20->10): writes features 0..15 only; stale 16..31 are killed
        // by w9's zero columns (k>10 of w9 frag is zero).
        layer<1, 1, 10>(s_w + 27 * 512, act, lane, lr, kg, z4);

        // final layer 10->1 (+ReLU): feature 0 lives in kg==0, reg 0.
        {
            const half8 wf = *(const half8*)(s_w + 28 * 512 + lane * 8);
            const half8 bf = *(const half8*)(act + lane * 8);
            f32x4 accF =
                __builtin_amdgcn_mfma_f32_16x16x32_f16(wf, bf, z4, 0, 0, 0);
            if (kg == 0) out[row0 + lr] = fmaxf(accF[0], 0.0f);
        }
    }
}

extern "C" void kernel_launch(void* const* d_in, const int* in_sizes, int n_in,
                              void* d_out, int out_size, void* d_ws, size_t ws_size,
                              hipStream_t stream) {
    const float* x = (const float*)d_in[0];
    const float* W0 = (const float*)d_in[1];
    const float* b0 = (const float*)d_in[2];
    const float* W1 = (const float*)d_in[3];
    const float* b1 = (const float*)d_in[4];
    const float* W2 = (const float*)d_in[5];
    const float* b2 = (const float*)d_in[6];
    const float* W3 = (const float*)d_in[7];
    const float* b3 = (const float*)d_in[8];
    const float* W4 = (const float*)d_in[9];
    const float* b4 = (const float*)d_in[10];
    const float* W5 = (const float*)d_in[11];
    const float* b5 = (const float*)d_in[12];
    const float* W6 = (const float*)d_in[13];
    const float* b6 = (const float*)d_in[14];
    const float* W7 = (const float*)d_in[15];
    const float* b7 = (const float*)d_in[16];
    const float* W8 = (const float*)d_in[17];
    const float* b8 = (const float*)d_in[18];
    const float* W9 = (const float*)d_in[19];
    const float* b9 = (const float*)d_in[20];
    float* out = (float*)d_out;

    const int n = in_sizes[0] / 11;  // 2,000,000 rows
    const int grid = 768;            // 3 blocks/CU resident, persistent

    longnet_mlp_r6<<<grid, 512, 0, stream>>>(
        x, W0, b0, W1, b1, W2, b2, W3, b3, W4, b4, W5, b5, W6, b6, W7, b7, W8,
        b8, W9, b9, out, n);
}

// Round 7
// 196.826 us; speedup vs baseline: 1.6089x; 1.6089x over previous
//
#include <hip/hip_runtime.h>
#include <math.h>

// 10-layer MLP, fp16 MFMA (fp32 acc), 16-row tiles, grid-stride per wave.
// R7 = R5 shape (256 thr, launch_bounds(256,4): known-good 64 VGPR, no
// scratch spills) + R6 frag-packed activations (B-frag read = lane*16B
// linear, zero bank conflicts; validated correct in R6).
// R6's (512,6) forced regalloc to 40 VGPR -> 1GB/dispatch scratch traffic.
// Bias folded as augmented-K column (marker 1.0 at feature==OUT).

typedef _Float16 half8 __attribute__((ext_vector_type(8)));
typedef _Float16 half4 __attribute__((ext_vector_type(4)));
typedef _Float16 half2 __attribute__((ext_vector_type(2)));
typedef float f32x4 __attribute__((ext_vector_type(4)));

__device__ __forceinline__ float swish_f(float a) {
    float e = __expf(-a);
    return a * __builtin_amdgcn_rcpf(1.0f + e);
}

// One lane's 8 f16 of weight fragment (ot,kt): A-frag layout row=ot*16+lr,
// k=kt*32+kg*8+e. Column k==IN holds the bias (augmented-K); else zero-pad.
__device__ __forceinline__ half8 make_frag(const float* __restrict__ W,
                                           const float* __restrict__ b,
                                           int IN, int OUT, int ot, int kt,
                                           int lr, int kg) {
    const int r = ot * 16 + lr;
    half8 h;
#pragma unroll
    for (int e = 0; e < 8; ++e) {
        const int k = kt * 32 + kg * 8 + e;
        float v = 0.0f;
        if (r < OUT) {
            if (k < IN)
                v = W[r * IN + k];
            else if (k == IN)
                v = b[r];
        }
        h[e] = (_Float16)v;
    }
    return h;
}

// acc[ot][r] = feature ot*16+kg*4+r of sample lr (D^T). Swish all (pad accs
// are 0 -> swish 0), overwrite feature==OUT with 1.0 marker, cvt_pkrtz pack,
// one b64 store into the frag-packed act tile:
//   feature f of sample lr lives at (f>>5)*512 + (((f>>3)&3)*16 + lr)*8 + (f&7)
//   (f16 units); the 4 features of (ot,kg) share one run: kt=ot>>1,
//   lane-group (2ot+(kg>>1))&3, half-select kg&1.
template <int NOT, int OUT>
__device__ __forceinline__ void epilogue(const f32x4 (&acc)[NOT],
                                         _Float16* act, int lr, int kg) {
    const int kgl = kg & 1;
    const int kgh = kg >> 1;
#pragma unroll
    for (int ot = 0; ot < NOT; ++ot) {
        float v[4];
#pragma unroll
        for (int r = 0; r < 4; ++r) {
            v[r] = swish_f(acc[ot][r]);
            if (ot == OUT / 16 && ot * 16 + kg * 4 + r == OUT) v[r] = 1.0f;
        }
        auto lo = __builtin_amdgcn_cvt_pkrtz(v[0], v[1]);
        auto hi = __builtin_amdgcn_cvt_pkrtz(v[2], v[3]);
        union {
            half4 h4;
            half2 h2[2];
        } u;
        u.h2[0] = __builtin_bit_cast(half2, lo);
        u.h2[1] = __builtin_bit_cast(half2, hi);
        _Float16* p = act + (ot >> 1) * 512 +
                      (((2 * ot + kgh) & 3) * 16 + lr) * 8 + kgl * 4;
        *(half4*)p = u.h4;
    }
}

// One layer; weight frags + act frags both read at lane*16B (conflict-free).
template <int NOT, int NKT, int OUT>
__device__ __forceinline__ void layer(const _Float16* __restrict__ wb,
                                      _Float16* act, int lane, int lr, int kg,
                                      f32x4 z4) {
    f32x4 acc[NOT];
#pragma unroll
    for (int kt = 0; kt < NKT; ++kt) {
        const half8 bf = *(const half8*)(act + kt * 512 + lane * 8);
#pragma unroll
        for (int ot = 0; ot < NOT; ++ot) {
            const half8 wf =
                *(const half8*)(wb + (ot * NKT + kt) * 512 + lane * 8);
            acc[ot] = __builtin_amdgcn_mfma_f32_16x16x32_f16(
                wf, bf, kt == 0 ? z4 : acc[ot], 0, 0, 0);
        }
    }
    epilogue<NOT, OUT>(acc, act, lr, kg);
}

__global__ __launch_bounds__(256, 4) void longnet_mlp_r7(
    const float* __restrict__ x,
    const float* __restrict__ W0, const float* __restrict__ b0,
    const float* __restrict__ W1, const float* __restrict__ b1,
    const float* __restrict__ W2, const float* __restrict__ b2,
    const float* __restrict__ W3, const float* __restrict__ b3,
    const float* __restrict__ W4, const float* __restrict__ b4,
    const float* __restrict__ W5, const float* __restrict__ b5,
    const float* __restrict__ W6, const float* __restrict__ b6,
    const float* __restrict__ W7, const float* __restrict__ b7,
    const float* __restrict__ W8, const float* __restrict__ b8,
    const float* __restrict__ W9, const float* __restrict__ b9,
    float* __restrict__ out, int n) {
    // 29 weight frags x 1024 B = 29696 B + 4 waves x 2048 B act = 37888 B
    // -> 4 blocks/CU, 16 waves/CU.
    __shared__ __align__(16) _Float16 s_w[29 * 512];
    __shared__ __align__(16) _Float16 s_act[4 * 1024];

    const int tid = threadIdx.x;
    const int lane = tid & 63;
    const int wave = tid >> 6;
    const int lr = lane & 15;
    const int kg = lane >> 4;

    // ---- stage 29 weight frags into LDS (4 waves split round-robin) ----
    {
        const float* Wt[10] = {W0, W1, W2, W3, W4, W5, W6, W7, W8, W9};
        const float* bt[10] = {b0, b1, b2, b3, b4, b5, b6, b7, b8, b9};
        const int INs[10] = {11, 20, 20, 30, 30, 40, 40, 40, 20, 10};
        const int OUTs[10] = {20, 20, 30, 30, 40, 40, 40, 20, 10, 1};
        const int NOTs[10] = {2, 2, 2, 2, 3, 3, 3, 2, 1, 1};
        const int NKTs[10] = {1, 1, 1, 1, 1, 2, 2, 2, 1, 1};
        int f = 0;
        for (int L = 0; L < 10; ++L)
            for (int ot = 0; ot < NOTs[L]; ++ot)
                for (int kt = 0; kt < NKTs[L]; ++kt, ++f)
                    if ((f & 3) == wave) {
                        half8 h = make_frag(Wt[L], bt[L], INs[L], OUTs[L], ot,
                                            kt, lr, kg);
                        *(half8*)(s_w + f * 512 + lane * 8) = h;
                    }
    }

    _Float16* act = s_act + wave * 1024;
    // zero wave's act tile once; kt1 features 48..63 stay zero forever
    // (K-pad for the IN_P=64 layers, never written).
    {
        int* a32 = (int*)act;
#pragma unroll
        for (int i = 0; i < 8; ++i) a32[i * 64 + lane] = 0;
    }
    __syncthreads();

    const f32x4 z4 = (f32x4){0.f, 0.f, 0.f, 0.f};
    const int ntile = n >> 4;  // n = 2e6, divisible by 16
    const int step = (int)gridDim.x * 4;

    for (int t = blockIdx.x * 4 + wave; t < ntile; t += step) {
        const int row0 = t * 16;

        // layer-0 B-frag straight from global x: col=sample(lr), k=feature;
        // feature 11 = 1.0 bias marker. kg>=2 lanes are all K-pad (zero).
        half8 xb = {};
        if (kg < 2) {
            const float* xr = x + (size_t)(row0 + lr) * 11 + kg * 8;
#pragma unroll
            for (int e = 0; e < 8; ++e) {
                const int k = kg * 8 + e;
                float v = (k < 11) ? xr[e] : ((k == 11) ? 1.0f : 0.0f);
                xb[e] = (_Float16)v;
            }
        }

        // layer 0 from registers (x), rest act<->act in LDS.
        {
            f32x4 acc[2];
#pragma unroll
            for (int ot = 0; ot < 2; ++ot) {
                const half8 wf = *(const half8*)(s_w + ot * 512 + lane * 8);
                acc[ot] = __builtin_amdgcn_mfma_f32_16x16x32_f16(wf, xb, z4,
                                                                 0, 0, 0);
            }
            epilogue<2, 20>(acc, act, lr, kg);
        }
        layer<2, 1, 20>(s_w + 2 * 512, act, lane, lr, kg, z4);
        layer<2, 1, 30>(s_w + 4 * 512, act, lane, lr, kg, z4);
        layer<2, 1, 30>(s_w + 6 * 512, act, lane, lr, kg, z4);
        layer<3, 1, 40>(s_w + 8 * 512, act, lane, lr, kg, z4);
        layer<3, 2, 40>(s_w + 11 * 512, act, lane, lr, kg, z4);
        layer<3, 2, 40>(s_w + 17 * 512, act, lane, lr, kg, z4);
        layer<2, 2, 20>(s_w + 23 * 512, act, lane, lr, kg, z4);
        // L8 (20->10): writes features 0..15 only; stale 16..31 are killed
        // by w9's zero columns (k>10 of w9 frag is zero).
        layer<1, 1, 10>(s_w + 27 * 512, act, lane, lr, kg, z4);

        // final layer 10->1 (+ReLU): feature 0 lives in kg==0, reg 0.
        {
            const half8 wf = *(const half8*)(s_w + 28 * 512 + lane * 8);
            const half8 bf = *(const half8*)(act + lane * 8);
            f32x4 accF =
                __builtin_amdgcn_mfma_f32_16x16x32_f16(wf, bf, z4, 0, 0, 0);
            if (kg == 0) out[row0 + lr] = fmaxf(accF[0], 0.0f);
        }
    }
}

extern "C" void kernel_launch(void* const* d_in, const int* in_sizes, int n_in,
                              void* d_out, int out_size, void* d_ws, size_t ws_size,
                              hipStream_t stream) {
    const float* x = (const float*)d_in[0];
    const float* W0 = (const float*)d_in[1];
    const float* b0 = (const float*)d_in[2];
    const float* W1 = (const float*)d_in[3];
    const float* b1 = (const float*)d_in[4];
    const float* W2 = (const float*)d_in[5];
    const float* b2 = (const float*)d_in[6];
    const float* W3 = (const float*)d_in[7];
    const float* b3 = (const float*)d_in[8];
    const float* W4 = (const float*)d_in[9];
    const float* b4 = (const float*)d_in[10];
    const float* W5 = (const float*)d_in[11];
    const float* b5 = (const float*)d_in[12];
    const float* W6 = (const float*)d_in[13];
    const float* b6 = (const float*)d_in[14];
    const float* W7 = (const float*)d_in[15];
    const float* b7 = (const float*)d_in[16];
    const float* W8 = (const float*)d_in[17];
    const float* b8 = (const float*)d_in[18];
    const float* W9 = (const float*)d_in[19];
    const float* b9 = (const float*)d_in[20];
    float* out = (float*)d_out;

    const int n = in_sizes[0] / 11;  // 2,000,000 rows
    const int grid = 1024;           // 4 blocks/CU resident, persistent

    longnet_mlp_r7<<<grid, 256, 0, stream>>>(
        x, W0, b0, W1, b1, W2, b2, W3, b3, W4, b4, W5, b5, W6, b6, W7, b7, W8,
        b8, W9, b9, out, n);
}